// Round 1
// baseline (93.272 us; speedup 1.0000x reference)
//
#include <hip/hip_runtime.h>
#include <stdint.h>

#define N 4096
#define D 512
#define TILE 128
#define BK 128           // fp8 bytes (=elems) per K-chunk
#define KITERS (D / BK)  // 4
#define NB (N / TILE)    // 32
#define NOFF (NB * (NB - 1) / 2)  // 496 strict-lower block pairs
#define NBLK (NB * (NB + 1) / 2)  // 528 total blocks

typedef float f32x4 __attribute__((ext_vector_type(4)));
typedef int   i32x8 __attribute__((ext_vector_type(8)));
typedef int   i32x4 __attribute__((ext_vector_type(4)));

// ---------------------------------------------------------------------------
// Kernel 1: fp32 -> fp8 e4m3 (OCP) conversion + fp32 row squared-norms.
// One wave per row: 512 elems / 64 lanes = 8 elems/lane (one 8B store).
// Norms are exact fp32; only the Gram term carries fp8 error.
// ---------------------------------------------------------------------------
__global__ __launch_bounds__(256) void prep_kernel(const float* __restrict__ x,
                                                   unsigned char* __restrict__ xq,
                                                   float* __restrict__ sq) {
    int row  = blockIdx.x * 4 + (threadIdx.x >> 6);
    int lane = threadIdx.x & 63;
    const float* xr = x + (size_t)row * D + lane * 8;
    float4 v0 = *reinterpret_cast<const float4*>(xr);
    float4 v1 = *reinterpret_cast<const float4*>(xr + 4);

    int w0 = __builtin_amdgcn_cvt_pk_fp8_f32(v0.x, v0.y, 0, false);
    w0     = __builtin_amdgcn_cvt_pk_fp8_f32(v0.z, v0.w, w0, true);
    int w1 = __builtin_amdgcn_cvt_pk_fp8_f32(v1.x, v1.y, 0, false);
    w1     = __builtin_amdgcn_cvt_pk_fp8_f32(v1.z, v1.w, w1, true);
    reinterpret_cast<int2*>(xq + (size_t)row * D)[lane] = make_int2(w0, w1);

    float s = v0.x * v0.x + v0.y * v0.y + v0.z * v0.z + v0.w * v0.w +
              v1.x * v1.x + v1.y * v1.y + v1.z * v1.z + v1.w * v1.w;
    #pragma unroll
    for (int off = 32; off > 0; off >>= 1) s += __shfl_down(s, off);
    if (lane == 0) sq[row] = s;
}

// ---------------------------------------------------------------------------
// Kernel 2: lower-triangle Gram via MX-scaled fp8 MFMA (K=128, unit scales)
// + fused distance epilogue. 128x128 tile, 4 waves each owning 64x64.
//
// v2 changes (this round):
//  - Double-buffered LDS K-pipeline (T3-lite): issue next tile's
//    global_load_lds BEFORE current tile's ds_read + 16 MFMA, one
//    __syncthreads per iter (was 2). The vmcnt(0) drain inside the sync is
//    now covered by ~600 cyc of compute instead of hitting raw L2 latency.
//  - sq[] row norms preloaded to registers BEFORE the K-loop (latency hidden
//    under staging) instead of after it.
//  - Nontemporal output stores: out is write-once, don't let 33.5 MB evict
//    the 2 MB fp8 panels from L2.
//  - v_sqrt_f32 approx (1 instr) instead of IEEE sqrtf fixup sequence; fp8
//    Gram error dominates the tolerance anyway.
//  - Diagonal blocks (bi==bj) mapped to the END of the grid: the 16-block
//    tail round (528 = 2*256 + 16) runs the cheapest blocks, and their
//    all-above-diagonal wave (wm=0,wn=1) skips fragment reads + MFMAs.
//
// LDS swizzle unchanged: row stride 128 B == 32 banks; glds forces contiguous
// LDS placement, so we XOR-swizzle the GLOBAL source address per lane: LDS
// slot (row, chunk) holds global 16B-chunk (chunk ^ (row&7)). Fragment reads
// then hit all 8 four-bank groups evenly -> LDS reads at the 8-clk/b128 floor.
// ---------------------------------------------------------------------------
__global__ __launch_bounds__(256, 2) void pairdist_kernel(const unsigned char* __restrict__ xq,
                                                          const float* __restrict__ sq,
                                                          float* __restrict__ out) {
    __shared__ __align__(16) unsigned char As[2][TILE * BK];  // 2 x 16 KB
    __shared__ __align__(16) unsigned char Bs[2][TILE * BK];  // 2 x 16 KB

    // Block map: t < NOFF -> strict lower-tri pair (bi > bj); t >= NOFF ->
    // diagonal (bi == bj), launched last.
    int t = blockIdx.x;
    int bi, bj;
    if (t >= NOFF) {
        bi = bj = t - NOFF;
    } else {
        bi = (int)((sqrtf(8.0f * (float)t + 1.0f) + 1.0f) * 0.5f);
        while (bi * (bi - 1) / 2 > t) bi--;
        while ((bi + 1) * bi / 2 <= t) bi++;
        bj = t - bi * (bi - 1) / 2;
    }

    int tid  = threadIdx.x;
    int w    = tid >> 6;        // wave 0..3
    int lane = tid & 63;
    int quad = lane >> 4;       // 0..3
    int lr   = lane & 15;       // 0..15
    int wm   = w >> 1;          // wave row (0..1) -> 64 rows
    int wn   = w & 1;           // wave col (0..1) -> 64 cols

    // Diagonal blocks: wave (wm=0,wn=1) covers i in [0,64), j in [64,128):
    // all j > i, zero outputs -> skip its fragment reads + MFMAs entirely.
    // (It still stages its 32 rows and hits every barrier.)
    const bool active = (bi != bj) || (wm >= wn);

    // Staging: wave w stages rows [w*32, w*32+32) of each 128x128B panel via
    // 4 glds (8 rows each). lane l -> row l>>3, chunk l&7 in LDS; source
    // chunk = (l&7) ^ (l>>3), implementing the XOR swizzle.
    int srow   = lane >> 3;                 // 0..7
    int schunk = lane & 7;                  // 16B chunk
    int sw     = ((schunk ^ srow) << 4);    // swizzled byte offset in row
    const unsigned char* ga = xq + (size_t)(bi * TILE + w * 32 + srow) * D + sw;
    const unsigned char* gb = xq + (size_t)(bj * TILE + w * 32 + srow) * D + sw;
    const int lbase = w * 32 * BK;          // wave-uniform LDS base in panel

    // Preload row norms NOW: 20 independent L2 loads whose latency hides
    // under tile-0 staging + the K-loop (they were previously issued in the
    // epilogue with nothing to hide behind).
    int ibase = bi * TILE + wm * 64;
    int jbase = bj * TILE + wn * 64;
    float sqi[4][4], sqj[4];
    #pragma unroll
    for (int mt = 0; mt < 4; mt++)
        #pragma unroll
        for (int tt = 0; tt < 4; tt++)
            sqi[mt][tt] = sq[ibase + mt * 16 + quad * 4 + tt];
    #pragma unroll
    for (int nt = 0; nt < 4; nt++)
        sqj[nt] = sq[jbase + nt * 16 + lr];

    f32x4 acc[4][4];
    #pragma unroll
    for (int mt = 0; mt < 4; mt++)
        #pragma unroll
        for (int nt = 0; nt < 4; nt++)
            acc[mt][nt] = (f32x4)0.0f;

    // -------- prologue: stage tile 0 into buffer 0 --------
    #pragma unroll
    for (int g = 0; g < 4; g++) {
        __builtin_amdgcn_global_load_lds(
            (const __attribute__((address_space(1))) void*)(ga + (size_t)g * 8 * D),
            (__attribute__((address_space(3))) void*)(&As[0][lbase + g * 8 * BK]), 16, 0, 0);
        __builtin_amdgcn_global_load_lds(
            (const __attribute__((address_space(1))) void*)(gb + (size_t)g * 8 * D),
            (__attribute__((address_space(3))) void*)(&Bs[0][lbase + g * 8 * BK]), 16, 0, 0);
    }
    __syncthreads();  // tile 0 staged (vmcnt(0) inside sync)

    // -------- pipelined K-loop: 1 barrier/iter, stage-issue covered --------
    #pragma unroll
    for (int it = 0; it < KITERS; it++) {
        const int curb = it & 1;

        if (it + 1 < KITERS) {
            const int nxt = curb ^ 1;
            const int k0  = (it + 1) * BK;
            #pragma unroll
            for (int g = 0; g < 4; g++) {
                __builtin_amdgcn_global_load_lds(
                    (const __attribute__((address_space(1))) void*)(ga + k0 + (size_t)g * 8 * D),
                    (__attribute__((address_space(3))) void*)(&As[nxt][lbase + g * 8 * BK]), 16, 0, 0);
                __builtin_amdgcn_global_load_lds(
                    (const __attribute__((address_space(1))) void*)(gb + k0 + (size_t)g * 8 * D),
                    (__attribute__((address_space(3))) void*)(&Bs[nxt][lbase + g * 8 * BK]), 16, 0, 0);
            }
        }

        if (active) {
            // Fragment layout (16x16x128 f8f6f4): lane holds A[m=lr][k=quad*32+j],
            // 32 B = 2 x b128. Swizzle: global chunk m lives at LDS chunk
            // m ^ (lr&7); chunks 2q and 2q+1 -> c0 and c0^16.
            int c0 = (((2 * quad) ^ (lr & 7)) << 4);
            int c1 = c0 ^ 16;
            i32x8 af[4], bfr[4];
            #pragma unroll
            for (int mt = 0; mt < 4; mt++) {
                const unsigned char* rb = &As[curb][(wm * 64 + mt * 16 + lr) * BK];
                i32x4 lo = *reinterpret_cast<const i32x4*>(rb + c0);
                i32x4 hi = *reinterpret_cast<const i32x4*>(rb + c1);
                af[mt][0] = lo[0]; af[mt][1] = lo[1]; af[mt][2] = lo[2]; af[mt][3] = lo[3];
                af[mt][4] = hi[0]; af[mt][5] = hi[1]; af[mt][6] = hi[2]; af[mt][7] = hi[3];
            }
            #pragma unroll
            for (int nt = 0; nt < 4; nt++) {
                const unsigned char* rb = &Bs[curb][(wn * 64 + nt * 16 + lr) * BK];
                i32x4 lo = *reinterpret_cast<const i32x4*>(rb + c0);
                i32x4 hi = *reinterpret_cast<const i32x4*>(rb + c1);
                bfr[nt][0] = lo[0]; bfr[nt][1] = lo[1]; bfr[nt][2] = lo[2]; bfr[nt][3] = lo[3];
                bfr[nt][4] = hi[0]; bfr[nt][5] = hi[1]; bfr[nt][6] = hi[2]; bfr[nt][7] = hi[3];
            }

            #pragma unroll
            for (int mt = 0; mt < 4; mt++)
                #pragma unroll
                for (int nt = 0; nt < 4; nt++)
                    acc[mt][nt] = __builtin_amdgcn_mfma_scale_f32_16x16x128_f8f6f4(
                        af[mt], bfr[nt], acc[mt][nt],
                        0, 0,                 // cbsz=0 (A fp8 e4m3), blgp=0 (B fp8 e4m3)
                        0, 0x7F7F7F7F,        // A scale: e8m0 127 = x1.0
                        0, 0x7F7F7F7F);       // B scale: x1.0
        }

        if (it + 1 < KITERS)
            __syncthreads();  // next tile staged + all waves' ds_reads of curb done
    }

    // Epilogue: D[m][n] at lane: n = lane&15, m = quad*4 + reg (shape-
    // determined C/D layout — same as 16x16 bf16).
    if (bi != bj) {
        // Fully-below-diagonal block: all j < i guaranteed -> no predicate
        #pragma unroll
        for (int mt = 0; mt < 4; mt++) {
            #pragma unroll
            for (int tt = 0; tt < 4; tt++) {
                int i = ibase + mt * 16 + quad * 4 + tt;
                unsigned rowoff = (unsigned)(i * (i - 1) / 2);
                #pragma unroll
                for (int nt = 0; nt < 4; nt++) {
                    int j = jbase + nt * 16 + lr;
                    float d2 = sqi[mt][tt] + sqj[nt] - 2.0f * acc[mt][nt][tt];
                    float dd = __builtin_amdgcn_sqrtf(fmaxf(d2, 0.0f));
                    __builtin_nontemporal_store(dd, &out[rowoff + (unsigned)j]);
                }
            }
        }
    } else {
        #pragma unroll
        for (int mt = 0; mt < 4; mt++) {
            #pragma unroll
            for (int tt = 0; tt < 4; tt++) {
                int i = ibase + mt * 16 + quad * 4 + tt;
                unsigned rowoff = (unsigned)(i * (i - 1) / 2);
                #pragma unroll
                for (int nt = 0; nt < 4; nt++) {
                    int j = jbase + nt * 16 + lr;
                    if (j < i) {
                        float d2 = sqi[mt][tt] + sqj[nt] - 2.0f * acc[mt][nt][tt];
                        float dd = __builtin_amdgcn_sqrtf(fmaxf(d2, 0.0f));
                        __builtin_nontemporal_store(dd, &out[rowoff + (unsigned)j]);
                    }
                }
            }
        }
    }
}

extern "C" void kernel_launch(void* const* d_in, const int* in_sizes, int n_in,
                              void* d_out, int out_size, void* d_ws, size_t ws_size,
                              hipStream_t stream) {
    const float* x = (const float*)d_in[0];
    float* out = (float*)d_out;

    // Workspace layout: [0, 2MB) fp8 copy of x; then 16KB of fp32 row norms.
    unsigned char* xq = (unsigned char*)d_ws;
    float* sq = (float*)((char*)d_ws + (size_t)N * D);

    prep_kernel<<<N / 4, 256, 0, stream>>>(x, xq, sq);

    pairdist_kernel<<<NBLK, 256, 0, stream>>>(xq, sq, out);
}

// Round 2
// 83.676 us; speedup vs baseline: 1.1147x; 1.1147x over previous
//
#include <hip/hip_runtime.h>
#include <stdint.h>

#define N 4096
#define D 512
#define TILE 128
#define BK 128           // fp8 bytes (=elems) per K-chunk
#define KITERS (D / BK)  // 4
#define NB (N / TILE)    // 32
#define NOFF (NB * (NB - 1) / 2)  // 496 strict-lower block pairs
#define NBLK (NB * (NB + 1) / 2)  // 528 total blocks

typedef float f32x4 __attribute__((ext_vector_type(4)));
typedef int   i32x8 __attribute__((ext_vector_type(8)));
typedef int   i32x4 __attribute__((ext_vector_type(4)));

// ---------------------------------------------------------------------------
// Kernel 1: fp32 -> fp8 e4m3 (OCP) conversion + fp32 row squared-norms.
// One wave per row: 512 elems / 64 lanes = 8 elems/lane (one 8B store).
// Norms are exact fp32; only the Gram term carries fp8 error.
// ---------------------------------------------------------------------------
__global__ __launch_bounds__(256) void prep_kernel(const float* __restrict__ x,
                                                   unsigned char* __restrict__ xq,
                                                   float* __restrict__ sq) {
    int row  = blockIdx.x * 4 + (threadIdx.x >> 6);
    int lane = threadIdx.x & 63;
    const float* xr = x + (size_t)row * D + lane * 8;
    float4 v0 = *reinterpret_cast<const float4*>(xr);
    float4 v1 = *reinterpret_cast<const float4*>(xr + 4);

    int w0 = __builtin_amdgcn_cvt_pk_fp8_f32(v0.x, v0.y, 0, false);
    w0     = __builtin_amdgcn_cvt_pk_fp8_f32(v0.z, v0.w, w0, true);
    int w1 = __builtin_amdgcn_cvt_pk_fp8_f32(v1.x, v1.y, 0, false);
    w1     = __builtin_amdgcn_cvt_pk_fp8_f32(v1.z, v1.w, w1, true);
    reinterpret_cast<int2*>(xq + (size_t)row * D)[lane] = make_int2(w0, w1);

    float s = v0.x * v0.x + v0.y * v0.y + v0.z * v0.z + v0.w * v0.w +
              v1.x * v1.x + v1.y * v1.y + v1.z * v1.z + v1.w * v1.w;
    #pragma unroll
    for (int off = 32; off > 0; off >>= 1) s += __shfl_down(s, off);
    if (lane == 0) sq[row] = s;
}

// ---------------------------------------------------------------------------
// Kernel 2: lower-triangle Gram via MX-scaled fp8 MFMA (K=128, unit scales)
// + fused distance epilogue. 128x128 tile, 4 waves each owning 64x64.
//
// v3 (ablation round): v2 minus the two suspected regressions.
//  KEEP:
//  - Double-buffered LDS K-pipeline: issue next tile's global_load_lds
//    BEFORE current tile's ds_read + 16 MFMA, one __syncthreads per iter
//    (v1 had 2/iter with a raw-latency vmcnt(0) drain between issue and use).
//  - Diagonal blocks (bi==bj) mapped to the END of the grid; their all-above-
//    diagonal wave (wm=0,wn=1) skips fragment reads + MFMAs.
//  - v_sqrt_f32 (single instr) instead of IEEE sqrtf fixup sequence.
//  REVERT (suspected causes of the 81->93 regression):
//  - Nontemporal output stores -> plain cached stores. NT bypasses L2 write-
//    combining; epilogue stores are 4x scattered 64B segments per instr that
//    NEED L2 merging into full lines. (primary suspect, ~magnitude match)
//  - sq[] preload before K-loop -> back to epilogue loads. 20 VGPRs live
//    across the loop risked spills under launch_bounds(256,2); saves <1 us.
//
// LDS swizzle unchanged: row stride 128 B == 32 banks; glds forces contiguous
// LDS placement, so we XOR-swizzle the GLOBAL source address per lane: LDS
// slot (row, chunk) holds global 16B-chunk (chunk ^ (row&7)). Fragment reads
// then hit all 8 four-bank groups evenly -> LDS reads at the 8-clk/b128 floor.
// ---------------------------------------------------------------------------
__global__ __launch_bounds__(256, 2) void pairdist_kernel(const unsigned char* __restrict__ xq,
                                                          const float* __restrict__ sq,
                                                          float* __restrict__ out) {
    __shared__ __align__(16) unsigned char As[2][TILE * BK];  // 2 x 16 KB
    __shared__ __align__(16) unsigned char Bs[2][TILE * BK];  // 2 x 16 KB

    // Block map: t < NOFF -> strict lower-tri pair (bi > bj); t >= NOFF ->
    // diagonal (bi == bj), launched last (cheapest blocks in the tail round).
    int t = blockIdx.x;
    int bi, bj;
    if (t >= NOFF) {
        bi = bj = t - NOFF;
    } else {
        bi = (int)((sqrtf(8.0f * (float)t + 1.0f) + 1.0f) * 0.5f);
        while (bi * (bi - 1) / 2 > t) bi--;
        while ((bi + 1) * bi / 2 <= t) bi++;
        bj = t - bi * (bi - 1) / 2;
    }

    int tid  = threadIdx.x;
    int w    = tid >> 6;        // wave 0..3
    int lane = tid & 63;
    int quad = lane >> 4;       // 0..3
    int lr   = lane & 15;       // 0..15
    int wm   = w >> 1;          // wave row (0..1) -> 64 rows
    int wn   = w & 1;           // wave col (0..1) -> 64 cols

    // Diagonal blocks: wave (wm=0,wn=1) covers i in [0,64), j in [64,128):
    // all j > i, zero outputs -> skip its fragment reads + MFMAs entirely.
    // (It still stages its 32 rows and hits every barrier.)
    const bool active = (bi != bj) || (wm >= wn);

    // Staging: wave w stages rows [w*32, w*32+32) of each 128x128B panel via
    // 4 glds (8 rows each). lane l -> row l>>3, chunk l&7 in LDS; source
    // chunk = (l&7) ^ (l>>3), implementing the XOR swizzle.
    int srow   = lane >> 3;                 // 0..7
    int schunk = lane & 7;                  // 16B chunk
    int sw     = ((schunk ^ srow) << 4);    // swizzled byte offset in row
    const unsigned char* ga = xq + (size_t)(bi * TILE + w * 32 + srow) * D + sw;
    const unsigned char* gb = xq + (size_t)(bj * TILE + w * 32 + srow) * D + sw;
    const int lbase = w * 32 * BK;          // wave-uniform LDS base in panel

    f32x4 acc[4][4];
    #pragma unroll
    for (int mt = 0; mt < 4; mt++)
        #pragma unroll
        for (int nt = 0; nt < 4; nt++)
            acc[mt][nt] = (f32x4)0.0f;

    // -------- prologue: stage tile 0 into buffer 0 --------
    #pragma unroll
    for (int g = 0; g < 4; g++) {
        __builtin_amdgcn_global_load_lds(
            (const __attribute__((address_space(1))) void*)(ga + (size_t)g * 8 * D),
            (__attribute__((address_space(3))) void*)(&As[0][lbase + g * 8 * BK]), 16, 0, 0);
        __builtin_amdgcn_global_load_lds(
            (const __attribute__((address_space(1))) void*)(gb + (size_t)g * 8 * D),
            (__attribute__((address_space(3))) void*)(&Bs[0][lbase + g * 8 * BK]), 16, 0, 0);
    }
    __syncthreads();  // tile 0 staged (vmcnt(0) inside sync)

    // -------- pipelined K-loop: 1 barrier/iter, stage-issue covered --------
    #pragma unroll
    for (int it = 0; it < KITERS; it++) {
        const int curb = it & 1;

        if (it + 1 < KITERS) {
            const int nxt = curb ^ 1;
            const int k0  = (it + 1) * BK;
            #pragma unroll
            for (int g = 0; g < 4; g++) {
                __builtin_amdgcn_global_load_lds(
                    (const __attribute__((address_space(1))) void*)(ga + k0 + (size_t)g * 8 * D),
                    (__attribute__((address_space(3))) void*)(&As[nxt][lbase + g * 8 * BK]), 16, 0, 0);
                __builtin_amdgcn_global_load_lds(
                    (const __attribute__((address_space(1))) void*)(gb + k0 + (size_t)g * 8 * D),
                    (__attribute__((address_space(3))) void*)(&Bs[nxt][lbase + g * 8 * BK]), 16, 0, 0);
            }
        }

        if (active) {
            // Fragment layout (16x16x128 f8f6f4): lane holds A[m=lr][k=quad*32+j],
            // 32 B = 2 x b128. Swizzle: global chunk m lives at LDS chunk
            // m ^ (lr&7); chunks 2q and 2q+1 -> c0 and c0^16.
            int c0 = (((2 * quad) ^ (lr & 7)) << 4);
            int c1 = c0 ^ 16;
            i32x8 af[4], bfr[4];
            #pragma unroll
            for (int mt = 0; mt < 4; mt++) {
                const unsigned char* rb = &As[curb][(wm * 64 + mt * 16 + lr) * BK];
                i32x4 lo = *reinterpret_cast<const i32x4*>(rb + c0);
                i32x4 hi = *reinterpret_cast<const i32x4*>(rb + c1);
                af[mt][0] = lo[0]; af[mt][1] = lo[1]; af[mt][2] = lo[2]; af[mt][3] = lo[3];
                af[mt][4] = hi[0]; af[mt][5] = hi[1]; af[mt][6] = hi[2]; af[mt][7] = hi[3];
            }
            #pragma unroll
            for (int nt = 0; nt < 4; nt++) {
                const unsigned char* rb = &Bs[curb][(wn * 64 + nt * 16 + lr) * BK];
                i32x4 lo = *reinterpret_cast<const i32x4*>(rb + c0);
                i32x4 hi = *reinterpret_cast<const i32x4*>(rb + c1);
                bfr[nt][0] = lo[0]; bfr[nt][1] = lo[1]; bfr[nt][2] = lo[2]; bfr[nt][3] = lo[3];
                bfr[nt][4] = hi[0]; bfr[nt][5] = hi[1]; bfr[nt][6] = hi[2]; bfr[nt][7] = hi[3];
            }

            #pragma unroll
            for (int mt = 0; mt < 4; mt++)
                #pragma unroll
                for (int nt = 0; nt < 4; nt++)
                    acc[mt][nt] = __builtin_amdgcn_mfma_scale_f32_16x16x128_f8f6f4(
                        af[mt], bfr[nt], acc[mt][nt],
                        0, 0,                 // cbsz=0 (A fp8 e4m3), blgp=0 (B fp8 e4m3)
                        0, 0x7F7F7F7F,        // A scale: e8m0 127 = x1.0
                        0, 0x7F7F7F7F);       // B scale: x1.0
        }

        if (it + 1 < KITERS)
            __syncthreads();  // next tile staged + all waves' ds_reads of curb done
    }

    // Epilogue: D[m][n] at lane: n = lane&15, m = quad*4 + reg (shape-
    // determined C/D layout — same as 16x16 bf16). sq loads here (once per
    // block, latency ~L2-hit, <1us total) keep them out of the K-loop's
    // live range.
    int ibase = bi * TILE + wm * 64;
    int jbase = bj * TILE + wn * 64;

    float sqi[4][4], sqj[4];
    #pragma unroll
    for (int mt = 0; mt < 4; mt++)
        #pragma unroll
        for (int tt = 0; tt < 4; tt++)
            sqi[mt][tt] = sq[ibase + mt * 16 + quad * 4 + tt];
    #pragma unroll
    for (int nt = 0; nt < 4; nt++)
        sqj[nt] = sq[jbase + nt * 16 + lr];

    if (bi != bj) {
        // Fully-below-diagonal block: all j < i guaranteed -> no predicate
        #pragma unroll
        for (int mt = 0; mt < 4; mt++) {
            #pragma unroll
            for (int tt = 0; tt < 4; tt++) {
                int i = ibase + mt * 16 + quad * 4 + tt;
                unsigned rowoff = (unsigned)(i * (i - 1) / 2);
                #pragma unroll
                for (int nt = 0; nt < 4; nt++) {
                    int j = jbase + nt * 16 + lr;
                    float d2 = sqi[mt][tt] + sqj[nt] - 2.0f * acc[mt][nt][tt];
                    out[rowoff + (unsigned)j] = __builtin_amdgcn_sqrtf(fmaxf(d2, 0.0f));
                }
            }
        }
    } else {
        #pragma unroll
        for (int mt = 0; mt < 4; mt++) {
            #pragma unroll
            for (int tt = 0; tt < 4; tt++) {
                int i = ibase + mt * 16 + quad * 4 + tt;
                unsigned rowoff = (unsigned)(i * (i - 1) / 2);
                #pragma unroll
                for (int nt = 0; nt < 4; nt++) {
                    int j = jbase + nt * 16 + lr;
                    if (j < i) {
                        float d2 = sqi[mt][tt] + sqj[nt] - 2.0f * acc[mt][nt][tt];
                        out[rowoff + (unsigned)j] = __builtin_amdgcn_sqrtf(fmaxf(d2, 0.0f));
                    }
                }
            }
        }
    }
}

extern "C" void kernel_launch(void* const* d_in, const int* in_sizes, int n_in,
                              void* d_out, int out_size, void* d_ws, size_t ws_size,
                              hipStream_t stream) {
    const float* x = (const float*)d_in[0];
    float* out = (float*)d_out;

    // Workspace layout: [0, 2MB) fp8 copy of x; then 16KB of fp32 row norms.
    unsigned char* xq = (unsigned char*)d_ws;
    float* sq = (float*)((char*)d_ws + (size_t)N * D);

    prep_kernel<<<N / 4, 256, 0, stream>>>(x, xq, sq);

    pairdist_kernel<<<NBLK, 256, 0, stream>>>(xq, sq, out);
}

// Round 3
// 79.593 us; speedup vs baseline: 1.1719x; 1.0513x over previous
//
#include <hip/hip_runtime.h>
#include <stdint.h>

#define N 4096
#define D 512
#define TILE 128
#define BK 128           // fp8 bytes (=elems) per K-chunk
#define KITERS (D / BK)  // 4
#define NB (N / TILE)    // 32
#define NOFF (NB * (NB - 1) / 2)  // 496 strict-lower block pairs
#define NBLK (NB * (NB + 1) / 2)  // 528 total blocks

typedef float f32x4 __attribute__((ext_vector_type(4)));
typedef int   i32x8 __attribute__((ext_vector_type(8)));
typedef int   i32x4 __attribute__((ext_vector_type(4)));

// ---------------------------------------------------------------------------
// Kernel 1: fp32 -> fp8 e4m3 (OCP) conversion + fp32 row squared-norms.
// One wave per row: 512 elems / 64 lanes = 8 elems/lane (one 8B store).
// Norms are exact fp32; only the Gram term carries fp8 error.
// ---------------------------------------------------------------------------
__global__ __launch_bounds__(256) void prep_kernel(const float* __restrict__ x,
                                                   unsigned char* __restrict__ xq,
                                                   float* __restrict__ sq) {
    int row  = blockIdx.x * 4 + (threadIdx.x >> 6);
    int lane = threadIdx.x & 63;
    const float* xr = x + (size_t)row * D + lane * 8;
    float4 v0 = *reinterpret_cast<const float4*>(xr);
    float4 v1 = *reinterpret_cast<const float4*>(xr + 4);

    int w0 = __builtin_amdgcn_cvt_pk_fp8_f32(v0.x, v0.y, 0, false);
    w0     = __builtin_amdgcn_cvt_pk_fp8_f32(v0.z, v0.w, w0, true);
    int w1 = __builtin_amdgcn_cvt_pk_fp8_f32(v1.x, v1.y, 0, false);
    w1     = __builtin_amdgcn_cvt_pk_fp8_f32(v1.z, v1.w, w1, true);
    reinterpret_cast<int2*>(xq + (size_t)row * D)[lane] = make_int2(w0, w1);

    float s = v0.x * v0.x + v0.y * v0.y + v0.z * v0.z + v0.w * v0.w +
              v1.x * v1.x + v1.y * v1.y + v1.z * v1.z + v1.w * v1.w;
    #pragma unroll
    for (int off = 32; off > 0; off >>= 1) s += __shfl_down(s, off);
    if (lane == 0) sq[row] = s;
}

// ---------------------------------------------------------------------------
// Kernel 2: lower-triangle Gram via MX-scaled fp8 MFMA (K=128, unit scales)
// + fused distance epilogue. 128x128 tile, 4 waves each owning 64x64.
//
// v4: occupancy round. Diagnosis: kernel is stall-bound (pipe-throughput
// floor ~5x below observed time); v3 proved intra-block pipelining is a
// null (matches learn_hip m99/m100). The lever is inter-block TLP, m97-style:
//  - SINGLE 32 KB LDS buffer (back to v1's 2-barrier K-loop).
//  - A-fragment STREAMING: hold bfr[4] (32 VGPR), load af per-mt (8 VGPR)
//    right before its 4 independent MFMAs. Cuts peak live set ~56 VGPR
//    (~190 -> ~140) so the kernel fits a 170-VGPR cap.
//  - __launch_bounds__(256, 3): 3 blocks/CU (LDS allows 5, VGPR cap 170
//    allows 3). Per-iter vmcnt(0) drains + epilogue store bursts now
//    overlap across 3 independent blocks instead of 2.
//  - KEEP from v2/v3: diag-last block remap (+ inactive-wave MFMA skip),
//    v_sqrt_f32. Cached (NOT nontemporal) stores — NT cost ~9.5 us (v2).
//
// LDS swizzle unchanged: row stride 128 B == 32 banks; glds forces contiguous
// LDS placement, so we XOR-swizzle the GLOBAL source address per lane: LDS
// slot (row, chunk) holds global 16B-chunk (chunk ^ (row&7)). Fragment reads
// then hit all 8 four-bank groups evenly -> LDS reads at the 8-clk/b128 floor.
// ---------------------------------------------------------------------------
__global__ __launch_bounds__(256, 3) void pairdist_kernel(const unsigned char* __restrict__ xq,
                                                          const float* __restrict__ sq,
                                                          float* __restrict__ out) {
    __shared__ __align__(16) unsigned char As[TILE * BK];  // 16 KB
    __shared__ __align__(16) unsigned char Bs[TILE * BK];  // 16 KB

    // Block map: t < NOFF -> strict lower-tri pair (bi > bj); t >= NOFF ->
    // diagonal (bi == bj), launched last (cheapest blocks in the tail round).
    int t = blockIdx.x;
    int bi, bj;
    if (t >= NOFF) {
        bi = bj = t - NOFF;
    } else {
        bi = (int)((sqrtf(8.0f * (float)t + 1.0f) + 1.0f) * 0.5f);
        while (bi * (bi - 1) / 2 > t) bi--;
        while ((bi + 1) * bi / 2 <= t) bi++;
        bj = t - bi * (bi - 1) / 2;
    }

    int tid  = threadIdx.x;
    int w    = tid >> 6;        // wave 0..3
    int lane = tid & 63;
    int quad = lane >> 4;       // 0..3
    int lr   = lane & 15;       // 0..15
    int wm   = w >> 1;          // wave row (0..1) -> 64 rows
    int wn   = w & 1;           // wave col (0..1) -> 64 cols

    // Diagonal blocks: wave (wm=0,wn=1) covers i in [0,64), j in [64,128):
    // all j > i, zero outputs -> skip its fragment reads + MFMAs entirely.
    // (It still stages its 32 rows and hits every barrier.)
    const bool active = (bi != bj) || (wm >= wn);

    // Staging: wave w stages rows [w*32, w*32+32) of each 128x128B panel via
    // 4 glds (8 rows each). lane l -> row l>>3, chunk l&7 in LDS; source
    // chunk = (l&7) ^ (l>>3), implementing the XOR swizzle.
    int srow   = lane >> 3;                 // 0..7
    int schunk = lane & 7;                  // 16B chunk
    int sw     = ((schunk ^ srow) << 4);    // swizzled byte offset in row
    const unsigned char* ga = xq + (size_t)(bi * TILE + w * 32 + srow) * D + sw;
    const unsigned char* gb = xq + (size_t)(bj * TILE + w * 32 + srow) * D + sw;
    unsigned char* la = As + w * 32 * BK;   // wave-uniform LDS bases
    unsigned char* lb = Bs + w * 32 * BK;

    f32x4 acc[4][4];
    #pragma unroll
    for (int mt = 0; mt < 4; mt++)
        #pragma unroll
        for (int nt = 0; nt < 4; nt++)
            acc[mt][nt] = (f32x4)0.0f;

    for (int k0 = 0; k0 < D; k0 += BK) {
        __syncthreads();   // prev iter's ds_reads done before overwrite
        #pragma unroll
        for (int g = 0; g < 4; g++) {
            __builtin_amdgcn_global_load_lds(
                (const __attribute__((address_space(1))) void*)(ga + k0 + (size_t)g * 8 * D),
                (__attribute__((address_space(3))) void*)(la + g * 8 * BK), 16, 0, 0);
            __builtin_amdgcn_global_load_lds(
                (const __attribute__((address_space(1))) void*)(gb + k0 + (size_t)g * 8 * D),
                (__attribute__((address_space(3))) void*)(lb + g * 8 * BK), 16, 0, 0);
        }
        __syncthreads();   // drains vmcnt(0): staging visible

        if (active) {
            // Fragment layout (16x16x128 f8f6f4): lane holds A[m=lr][k=quad*32+j],
            // 32 B = 2 x b128. Swizzle: global chunk m lives at LDS chunk
            // m ^ (lr&7); chunks 2q and 2q+1 -> c0 and c0^16.
            int c0 = (((2 * quad) ^ (lr & 7)) << 4);
            int c1 = c0 ^ 16;

            // B fragments resident for the whole iter (32 VGPR)...
            i32x8 bfr[4];
            #pragma unroll
            for (int nt = 0; nt < 4; nt++) {
                const unsigned char* rb = Bs + (wn * 64 + nt * 16 + lr) * BK;
                i32x4 lo = *reinterpret_cast<const i32x4*>(rb + c0);
                i32x4 hi = *reinterpret_cast<const i32x4*>(rb + c1);
                bfr[nt][0] = lo[0]; bfr[nt][1] = lo[1]; bfr[nt][2] = lo[2]; bfr[nt][3] = lo[3];
                bfr[nt][4] = hi[0]; bfr[nt][5] = hi[1]; bfr[nt][6] = hi[2]; bfr[nt][7] = hi[3];
            }
            // ...A fragment streamed per-mt (8 VGPR live at a time). The
            // compiler pipelines mt+1's ds_reads under mt's 4 MFMAs.
            #pragma unroll
            for (int mt = 0; mt < 4; mt++) {
                const unsigned char* rb = As + (wm * 64 + mt * 16 + lr) * BK;
                i32x4 lo = *reinterpret_cast<const i32x4*>(rb + c0);
                i32x4 hi = *reinterpret_cast<const i32x4*>(rb + c1);
                i32x8 af;
                af[0] = lo[0]; af[1] = lo[1]; af[2] = lo[2]; af[3] = lo[3];
                af[4] = hi[0]; af[5] = hi[1]; af[6] = hi[2]; af[7] = hi[3];
                #pragma unroll
                for (int nt = 0; nt < 4; nt++)
                    acc[mt][nt] = __builtin_amdgcn_mfma_scale_f32_16x16x128_f8f6f4(
                        af, bfr[nt], acc[mt][nt],
                        0, 0,                 // cbsz=0 (A fp8 e4m3), blgp=0 (B fp8 e4m3)
                        0, 0x7F7F7F7F,        // A scale: e8m0 127 = x1.0
                        0, 0x7F7F7F7F);       // B scale: x1.0
            }
        }
    }

    // Epilogue: D[m][n] at lane: n = lane&15, m = quad*4 + reg (shape-
    // determined C/D layout — same as 16x16 bf16). sq loads here (once per
    // block) keep them out of the K-loop's live range.
    int ibase = bi * TILE + wm * 64;
    int jbase = bj * TILE + wn * 64;

    float sqi[4][4], sqj[4];
    #pragma unroll
    for (int mt = 0; mt < 4; mt++)
        #pragma unroll
        for (int tt = 0; tt < 4; tt++)
            sqi[mt][tt] = sq[ibase + mt * 16 + quad * 4 + tt];
    #pragma unroll
    for (int nt = 0; nt < 4; nt++)
        sqj[nt] = sq[jbase + nt * 16 + lr];

    if (bi != bj) {
        // Fully-below-diagonal block: all j < i guaranteed -> no predicate
        #pragma unroll
        for (int mt = 0; mt < 4; mt++) {
            #pragma unroll
            for (int tt = 0; tt < 4; tt++) {
                int i = ibase + mt * 16 + quad * 4 + tt;
                unsigned rowoff = (unsigned)(i * (i - 1) / 2);
                #pragma unroll
                for (int nt = 0; nt < 4; nt++) {
                    int j = jbase + nt * 16 + lr;
                    float d2 = sqi[mt][tt] + sqj[nt] - 2.0f * acc[mt][nt][tt];
                    out[rowoff + (unsigned)j] = __builtin_amdgcn_sqrtf(fmaxf(d2, 0.0f));
                }
            }
        }
    } else {
        #pragma unroll
        for (int mt = 0; mt < 4; mt++) {
            #pragma unroll
            for (int tt = 0; tt < 4; tt++) {
                int i = ibase + mt * 16 + quad * 4 + tt;
                unsigned rowoff = (unsigned)(i * (i - 1) / 2);
                #pragma unroll
                for (int nt = 0; nt < 4; nt++) {
                    int j = jbase + nt * 16 + lr;
                    if (j < i) {
                        float d2 = sqi[mt][tt] + sqj[nt] - 2.0f * acc[mt][nt][tt];
                        out[rowoff + (unsigned)j] = __builtin_amdgcn_sqrtf(fmaxf(d2, 0.0f));
                    }
                }
            }
        }
    }
}

extern "C" void kernel_launch(void* const* d_in, const int* in_sizes, int n_in,
                              void* d_out, int out_size, void* d_ws, size_t ws_size,
                              hipStream_t stream) {
    const float* x = (const float*)d_in[0];
    float* out = (float*)d_out;

    // Workspace layout: [0, 2MB) fp8 copy of x; then 16KB of fp32 row norms.
    unsigned char* xq = (unsigned char*)d_ws;
    float* sq = (float*)((char*)d_ws + (size_t)N * D);

    prep_kernel<<<N / 4, 256, 0, stream>>>(x, xq, sq);

    pairdist_kernel<<<NBLK, 256, 0, stream>>>(xq, sq, out);
}